// Round 1
// baseline (117.860 us; speedup 1.0000x reference)
//
#include <hip/hip_runtime.h>
#include <math.h>

#define BB 1024
#define TT 1024
#define HH 256
#define CC 10

// State fold: track r where h = 1 - 2r.
//   z = wd*h + win*x + bh,  m = S*z  (S = 2*log2e)
//   m = A*r + q,  A = -2*wd*S,  q = fma(x, win*S, (bh + wd)*S)
//   t = exp2(m); r' = rcp(t + 1)
// Loop-carried chain: fma -> exp2 -> add -> rcp (4 ops).
// ILP restructure: each thread advances TWO independent chains (two batch
// rows) interleaved in program order, so the wave's own instruction stream
// hides the trans latency instead of relying on phase-aligned sibling waves.

__global__ __launch_bounds__(HH) void vanilla_rnn_kernel(
    const float* __restrict__ x,
    const float* __restrict__ W_hx,
    const float* __restrict__ W_hh,
    const float* __restrict__ b_h,
    const float* __restrict__ W_hp,
    const float* __restrict__ b_o,
    float* __restrict__ out)
{
    __shared__ float xs0[TT + 8];   // +2 float4 pad for prefetch tail
    __shared__ float xs1[TT + 8];
    __shared__ float part[2][CC * 4];

    const int tid = threadIdx.x;   // h index
    const int b0  = blockIdx.x * 2;

    // Stage both x rows (2 x 4 KB) into LDS: 256 threads x float4 each.
    ((float4*)xs0)[tid] = ((const float4*)(x + (size_t)b0 * TT))[tid];
    ((float4*)xs1)[tid] = ((const float4*)(x + (size_t)(b0 + 1) * TT))[tid];
    if (tid < 2) {
        ((float4*)xs0)[TT / 4 + tid] = make_float4(0.f, 0.f, 0.f, 0.f);
        ((float4*)xs1)[TT / 4 + tid] = make_float4(0.f, 0.f, 0.f, 0.f);
    }

    // Per-h constants (pre-scaled by S = 2*log2(e)) — shared by both chains.
    const float S    = 2.88539008177792681472f;
    const float winS = W_hx[tid] * S;
    const float wd   = W_hh[tid * HH + tid];
    const float A    = -2.0f * wd * S;
    const float bhS2 = (b_h[tid] + wd) * S;
    float whp[CC];
#pragma unroll
    for (int c = 0; c < CC; ++c) whp[c] = W_hp[c * HH + tid];

    __syncthreads();

    // Two serial recurrences over t, interleaved; distance-2 LDS prefetch.
    float r0 = 0.5f, r1 = 0.5f;           // h0 = 0  =>  r0 = 0.5
    const float4* xa = (const float4*)xs0;
    const float4* xb = (const float4*)xs1;
    float4 curA = xa[0], nxtA = xa[1];
    float4 curB = xb[0], nxtB = xb[1];
#pragma unroll 4
    for (int t4 = 0; t4 < TT / 4; ++t4) {
        float4 pfA = xa[t4 + 2];          // lands in pad on last two iters
        float4 pfB = xb[t4 + 2];
        float qa0 = fmaf(curA.x, winS, bhS2);
        float qa1 = fmaf(curA.y, winS, bhS2);
        float qa2 = fmaf(curA.z, winS, bhS2);
        float qa3 = fmaf(curA.w, winS, bhS2);
        float qb0 = fmaf(curB.x, winS, bhS2);
        float qb1 = fmaf(curB.y, winS, bhS2);
        float qb2 = fmaf(curB.z, winS, bhS2);
        float qb3 = fmaf(curB.w, winS, bhS2);
        float m0, m1, t0, t1;
        m0 = fmaf(A, r0, qa0);                  m1 = fmaf(A, r1, qb0);
        t0 = __builtin_amdgcn_exp2f(m0);        t1 = __builtin_amdgcn_exp2f(m1);
        r0 = __builtin_amdgcn_rcpf(t0 + 1.0f);  r1 = __builtin_amdgcn_rcpf(t1 + 1.0f);
        m0 = fmaf(A, r0, qa1);                  m1 = fmaf(A, r1, qb1);
        t0 = __builtin_amdgcn_exp2f(m0);        t1 = __builtin_amdgcn_exp2f(m1);
        r0 = __builtin_amdgcn_rcpf(t0 + 1.0f);  r1 = __builtin_amdgcn_rcpf(t1 + 1.0f);
        m0 = fmaf(A, r0, qa2);                  m1 = fmaf(A, r1, qb2);
        t0 = __builtin_amdgcn_exp2f(m0);        t1 = __builtin_amdgcn_exp2f(m1);
        r0 = __builtin_amdgcn_rcpf(t0 + 1.0f);  r1 = __builtin_amdgcn_rcpf(t1 + 1.0f);
        m0 = fmaf(A, r0, qa3);                  m1 = fmaf(A, r1, qb3);
        t0 = __builtin_amdgcn_exp2f(m0);        t1 = __builtin_amdgcn_exp2f(m1);
        r0 = __builtin_amdgcn_rcpf(t0 + 1.0f);  r1 = __builtin_amdgcn_rcpf(t1 + 1.0f);
        curA = nxtA; nxtA = pfA;
        curB = nxtB; nxtB = pfB;
    }
    float h0 = fmaf(-2.0f, r0, 1.0f);
    float h1 = fmaf(-2.0f, r1, 1.0f);

    // Projection: out[b,c] = sum_h h * W_hp[c,h] + b_o[c]  (for both rows)
    const int lane = tid & 63;
    const int wave = tid >> 6;
#pragma unroll
    for (int c = 0; c < CC; ++c) {
        float v0 = h0 * whp[c];
        float v1 = h1 * whp[c];
#pragma unroll
        for (int off = 32; off >= 1; off >>= 1) {
            v0 += __shfl_down(v0, off);
            v1 += __shfl_down(v1, off);
        }
        if (lane == 0) { part[0][c * 4 + wave] = v0; part[1][c * 4 + wave] = v1; }
    }
    __syncthreads();

    if (tid < 2 * CC) {
        const int bb = tid / CC;      // 0 or 1: which batch row
        const int c  = tid - bb * CC;
        float acc = b_o[c];
#pragma unroll
        for (int w = 0; w < 4; ++w) acc += part[bb][c * 4 + w];
        out[(size_t)(b0 + bb) * CC + c] = acc;
    }
}

extern "C" void kernel_launch(void* const* d_in, const int* in_sizes, int n_in,
                              void* d_out, int out_size, void* d_ws, size_t ws_size,
                              hipStream_t stream) {
    const float* x    = (const float*)d_in[0];
    const float* W_hx = (const float*)d_in[1];
    const float* W_hh = (const float*)d_in[2];
    const float* b_h  = (const float*)d_in[3];
    const float* W_hp = (const float*)d_in[4];
    const float* b_o  = (const float*)d_in[5];
    float* out = (float*)d_out;

    vanilla_rnn_kernel<<<BB / 2, HH, 0, stream>>>(x, W_hx, W_hh, b_h, W_hp, b_o, out);
}